// Round 8
// baseline (39.014 us; speedup 1.0000x reference)
//
#include <hip/hip_runtime.h>
#include <stdint.h>

#define HGT 100
#define WID 152
#define HW (HGT * WID)          // 15200
#define NINST 500
#define CIN 8
#define CH 8
#define NPARAMS 169
#define PPT 4                    // pixels per thread (one float4)
#define WPKN 144                 // packed words per instance
#define WPKSTRIDE 160            // u32 stride per instance in d_ws

// original param layout per instance (169 floats):
//   w0: [0,80) (8 x 10: wx, wy, f0..f7)  w1: [80,144)  w2: [144,152)
//   b0: [152,160)  b1: [160,168)  b2: [168]
// packed layout in d_ws (u32 = f16 duplicated in both halves):
//   [0,64):    w0 feature weights, idx c*8+i  <- P[c*10+2+i]
//   [64,128):  w1, idx c*8+i                  <- P[80+c*8+i]
//   [128,136): w2, idx i                      <- P[144+i]
//   [136,144): b1, idx c                      <- P[160+c]

typedef __fp16 h2 __attribute__((ext_vector_type(2)));

static __device__ __forceinline__ h2 bc(uint32_t u) { return __builtin_bit_cast(h2, u); }

static __device__ __forceinline__ h2 pkfma(h2 w, h2 x, h2 acc) {
    return __builtin_elementwise_fma(w, x, acc);      // v_pk_fma_f16
}

static __device__ __forceinline__ h2 hrelu(h2 a) {
    h2 z = {(__fp16)0.0f, (__fp16)0.0f};
    return __builtin_elementwise_max(a, z);            // v_pk_max_f16
}

static __device__ __forceinline__ h2 pack2(float lo, float hi) {
    h2 r = {(__fp16)lo, (__fp16)hi};                   // RNE converts
    return r;
}

__global__ __launch_bounds__(256) void pack_weights(
    const float* __restrict__ params, uint32_t* __restrict__ wpk)
{
    const int i = blockIdx.x * 256 + threadIdx.x;      // over NINST*WPKN
    if (i >= NINST * WPKN) return;
    const int n = i / WPKN;
    const int k = i - n * WPKN;
    const float* __restrict__ P = params + n * NPARAMS;
    float w;
    if (k < 64)       w = P[(k >> 3) * 10 + 2 + (k & 7)];
    else if (k < 128) w = P[80 + (k - 64)];
    else if (k < 136) w = P[144 + (k - 128)];
    else              w = P[160 + (k - 136)];
    const __fp16 h = (__fp16)w;                        // RNE
    const uint32_t u = (uint32_t)__builtin_bit_cast(uint16_t, h);
    wpk[n * WPKSTRIDE + k] = (u << 16) | u;
}

__global__ __launch_bounds__(256, 4) void dyn_mask_head(
    const float* __restrict__ feats,       // [2, 8, HW]
    const float* __restrict__ params,      // [500, 169] (f32 coords/biases)
    const uint32_t* __restrict__ wpk,      // packed f16 weights
    const float* __restrict__ locs,        // [500, 2]
    const float* __restrict__ soi,         // [500]
    const int*  __restrict__ im_inds,      // [500]
    float* __restrict__ out)               // [500, HW]
{
    const int n  = blockIdx.y;                               // instance
    const int q  = blockIdx.x * blockDim.x + threadIdx.x;    // float4 index
    const int p0 = q * PPT;                                  // first pixel
    if (p0 >= HW) return;

    // wave-uniform -> SGPRs
    const int   im      = im_inds[n];
    const float lx      = locs[n * 2 + 0];
    const float ly      = locs[n * 2 + 1];
    const float inv_soi = 1.0f / soi[n];
    const float* __restrict__ P = params + n * NPARAMS;
    const uint32_t* __restrict__ W = wpk + n * WPKSTRIDE;

    const int py  = p0 / WID;
    const int px0 = p0 - py * WID;
    const float rely = (ly - (float)(py * 8 + 4)) * inv_soi;     // f32
    float relx[PPT];
#pragma unroll
    for (int r = 0; r < PPT; ++r)
        relx[r] = (lx - (float)((px0 + r) * 8 + 4)) * inv_soi;   // f32

    // features: [channel][pixel-pair], f16x2 = (px0,px1) / (px2,px3)
    h2 f[CIN][2];
    const float* fb = feats + (size_t)im * CIN * HW + p0;
#pragma unroll
    for (int j = 0; j < CIN; ++j) {
        const float4 v = *reinterpret_cast<const float4*>(fb + (size_t)j * HW);
        f[j][0] = pack2(v.x, v.y);
        f[j][1] = pack2(v.z, v.w);
    }

    // ---- layer 0: 10 -> 8, relu. coord+bias in f32, features in pk f16 ----
    h2 h0[CH][2];
#pragma unroll
    for (int c = 0; c < CH; ++c) {
        const float s = fmaf(P[c * 10 + 1], rely, P[152 + c]);   // wy*rely + b0
        const float wx = P[c * 10 + 0];
        float sp[PPT];
#pragma unroll
        for (int r = 0; r < PPT; ++r) sp[r] = fmaf(wx, relx[r], s);
        h2 a0 = pack2(sp[0], sp[1]);
        h2 a1 = pack2(sp[2], sp[3]);
#pragma unroll
        for (int i = 0; i < CIN; ++i) {
            const h2 w = bc(W[c * 8 + i]);
            a0 = pkfma(w, f[i][0], a0);
            a1 = pkfma(w, f[i][1], a1);
        }
        h0[c][0] = hrelu(a0);
        h0[c][1] = hrelu(a1);
    }

    // ---- layer 1: 8 -> 8, relu ----
    h2 h1[CH][2];
#pragma unroll
    for (int c = 0; c < CH; ++c) {
        const h2 b1 = bc(W[136 + c]);
        h2 a0 = b1, a1 = b1;
#pragma unroll
        for (int i = 0; i < CH; ++i) {
            const h2 w = bc(W[64 + c * 8 + i]);
            a0 = pkfma(w, h0[i][0], a0);
            a1 = pkfma(w, h0[i][1], a1);
        }
        h1[c][0] = hrelu(a0);
        h1[c][1] = hrelu(a1);
    }

    // ---- layer 2: 8 -> 1 ----
    const float b2 = P[168];
    h2 o0 = pack2(b2, b2);
    h2 o1 = o0;
#pragma unroll
    for (int i = 0; i < CH; ++i) {
        const h2 w = bc(W[128 + i]);
        o0 = pkfma(w, h1[i][0], o0);
        o1 = pkfma(w, h1[i][1], o1);
    }

    float4 ov;
    ov.x = (float)o0.x; ov.y = (float)o0.y;
    ov.z = (float)o1.x; ov.w = (float)o1.y;
    *reinterpret_cast<float4*>(out + (size_t)n * HW + p0) = ov;
}

extern "C" void kernel_launch(void* const* d_in, const int* in_sizes, int n_in,
                              void* d_out, int out_size, void* d_ws, size_t ws_size,
                              hipStream_t stream) {
    const float* feats   = (const float*)d_in[0];  // mask_feats [2,8,100,152]
    const float* params  = (const float*)d_in[1];  // mask_head_params [500,169]
    const float* locs    = (const float*)d_in[2];  // instance_locations [500,2]
    const float* soi     = (const float*)d_in[3];  // soi [500]
    const int*   im_inds = (const int*)d_in[4];    // im_inds [500]
    float*       out     = (float*)d_out;          // [500,1,100,152]
    uint32_t*    wpk     = (uint32_t*)d_ws;        // 500*160 u32 = 320 KB

    const int total_pack = NINST * WPKN;                        // 72000
    pack_weights<<<(total_pack + 255) / 256, 256, 0, stream>>>(params, wpk);

    const int quads_per_inst = HW / PPT;                        // 3800
    dim3 block(256);
    dim3 grid((quads_per_inst + block.x - 1) / block.x, NINST); // (15, 500)
    dyn_mask_head<<<grid, block, 0, stream>>>(feats, params, wpk, locs, soi, im_inds, out);
}